// Round 6
// baseline (464.566 us; speedup 1.0000x reference)
//
#include <hip/hip_runtime.h>
#include <math.h>

// Problem constants
#define TT 80
#define BS 8
#define NA 6
#define DMODEL 768
#define NH 4
#define DH 192
#define FFD 1024
#define NROWS (TT*BS)   // 640
#define NQKV (3*DMODEL) // 2304

typedef __bf16 bf16;
typedef __bf16 bf16x8 __attribute__((ext_vector_type(8)));
typedef float  f32x4  __attribute__((ext_vector_type(4)));

// ---------------- block reduce (256 threads, 4 waves of 64) ----------------
__device__ __forceinline__ float block_reduce_sum256(float v, float* sm4) {
#pragma unroll
    for (int off = 32; off > 0; off >>= 1) v += __shfl_down(v, off, 64);
    int lane = threadIdx.x & 63, wid = threadIdx.x >> 6;
    if (lane == 0) sm4[wid] = v;
    __syncthreads();
    float r = sm4[0] + sm4[1] + sm4[2] + sm4[3];
    __syncthreads();
    return r;
}

// ---------------- embedding + positional encoding + h0 (f32 + bf16) ----------------
__global__ __launch_bounds__(256) void embed_k(
        const float* __restrict__ x, const int* __restrict__ y,
        const int* __restrict__ ind_map, const float* __restrict__ skel_W,
        const float* __restrict__ skel_b, const float* __restrict__ muQ,
        const float* __restrict__ sigQ, float* __restrict__ h0,
        bf16* __restrict__ h0b) {
    __shared__ float xrow[152];
    int r = blockIdx.x;
    int t = r >> 3, b = r & 7;
    int c = threadIdx.x;
    if (c < 150) xrow[c] = x[(b * 150 + c) * TT + t];
    __syncthreads();
    float acc = skel_b[c];
    for (int jf = 0; jf < 150; jf++) acc += xrow[jf] * skel_W[jf * 256 + c];
    int ind_t = ind_map[t * 8 + b];
    int yb = y[b * NA + ind_t];
    float cm = muQ[yb * 256 + c];
    float cs = sigQ[yb * 256 + c];
    int start = (t == 0) ? 0 : (t + 2);
    float div = expf((float)(c & ~1) * (-9.210340371976184f / 256.0f));
    float p0, p1, p2;
    if (c & 1) {
        p0 = cosf((float)start * div);
        p1 = cosf((float)(start + 1) * div);
        p2 = cosf((float)(start + 2) * div);
    } else {
        p0 = sinf((float)start * div);
        p1 = sinf((float)(start + 1) * div);
        p2 = sinf((float)(start + 2) * div);
    }
    float* hr = h0 + (size_t)r * DMODEL;
    float v0 = cm + p0, v1 = cs + p1, v2 = acc + p2;
    hr[c] = v0; hr[c + 256] = v1; hr[c + 512] = v2;
    bf16* hb = h0b + (size_t)r * DMODEL;
    hb[c] = (bf16)v0; hb[c + 256] = (bf16)v1; hb[c + 512] = (bf16)v2;
}

// ---------------- ALL-layer weight transpose + bf16 cast (one dispatch) ----------
__global__ __launch_bounds__(256) void transpose_k(
        const float* __restrict__ Wq, const float* __restrict__ Wk,
        const float* __restrict__ Wv, const float* __restrict__ Wo,
        const float* __restrict__ W1, const float* __restrict__ W2,
        bf16* __restrict__ qkvT, bf16* __restrict__ woT,
        bf16* __restrict__ w1T, bf16* __restrict__ w2T) {
    int lz = blockIdx.z;
    int l = lz >> 2, z = lz & 3;
    int K = (z == 3) ? 1024 : 768;
    int N = (z == 0) ? 2304 : (z == 2) ? 1024 : 768;
    int k0 = blockIdx.x * 32, n0 = blockIdx.y * 32;
    if (k0 >= K || n0 >= N) return;
    const float* src; bf16* dst; int ldsrc; int ncol;
    if (z == 0) {
        // 768 is NOT a power of two — subtract segment base (R2 bug).
        if (n0 < 768)       { src = Wq + (size_t)l * 768 * 768; ncol = n0; }
        else if (n0 < 1536) { src = Wk + (size_t)l * 768 * 768; ncol = n0 - 768; }
        else                { src = Wv + (size_t)l * 768 * 768; ncol = n0 - 1536; }
        dst = qkvT + (size_t)l * NQKV * DMODEL; ldsrc = 768;
    } else if (z == 1) { src = Wo + (size_t)l * 768 * 768;  dst = woT + (size_t)l * 768 * 768;  ldsrc = 768;  ncol = n0; }
    else if (z == 2)   { src = W1 + (size_t)l * 768 * 1024; dst = w1T + (size_t)l * 1024 * 768; ldsrc = 1024; ncol = n0; }
    else               { src = W2 + (size_t)l * 1024 * 768; dst = w2T + (size_t)l * 768 * 1024; ldsrc = 768;  ncol = n0; }
    __shared__ float tile[32][33];
    int tx = threadIdx.x & 31, ty = threadIdx.x >> 5;
#pragma unroll
    for (int i = 0; i < 4; i++) {
        int r = ty + 8 * i;
        tile[r][tx] = src[(size_t)(k0 + r) * ldsrc + ncol + tx];
    }
    __syncthreads();
#pragma unroll
    for (int i = 0; i < 4; i++) {
        int r = ty + 8 * i;
        dst[(size_t)(n0 + r) * K + k0 + tx] = (bf16)tile[tx][r];
    }
}

// ---------------- bf16 MFMA GEMM with fused-LN input / stats-producing output --
// AMODE 0: A is bf16 [M,K].
// AMODE 1: A is f32 [M,768] pre-LN; normalize on the fly using per-row stats
//          (inS/inQ, accumulated by a previous EPI-3 dispatch) and ag/ab; block
//          x==0 also writes the normalized f32 rows to aNormOut (next residual).
// EPI 0: QKV epilogue (bias by col segment, elu+1 on cols<1536, bf16 out)
// EPI 2: bias + relu, bf16 out
// EPI 3: bias + f32 resid, f32 out, and atomically accumulate per-row
//        sum/sumsq into outS/outQ (consumed by a later AMODE-1 dispatch).
template <int AMODE, int EPI>
__global__ __launch_bounds__(256) void gemm_mfma(
        const void* __restrict__ Asrc, const bf16* __restrict__ Bt,
        const float* __restrict__ bias0, const float* __restrict__ bias1,
        const float* __restrict__ bias2, const float* __restrict__ resid,
        const float* __restrict__ inS, const float* __restrict__ inQ,
        const float* __restrict__ ag, const float* __restrict__ ab,
        float* __restrict__ aNormOut,
        float* __restrict__ outF, bf16* __restrict__ outB,
        float* __restrict__ outS, float* __restrict__ outQ,
        int M, int N, int K) {
    __shared__ __attribute__((aligned(16))) bf16 As0[64][40];
    __shared__ __attribute__((aligned(16))) bf16 As1[64][40];
    __shared__ __attribute__((aligned(16))) bf16 Bs0[64][40];
    __shared__ __attribute__((aligned(16))) bf16 Bs1[64][40];
    int tid = threadIdx.x;
    int m0 = blockIdx.y * 64, n0 = blockIdx.x * 64;
    int w = tid >> 6;
    int l = tid & 63;
    int lm = l & 15, lq = l >> 4;
    int sr = tid >> 2;          // staging row 0..63
    int sk = (tid & 3) * 8;     // staging k offset within 32-chunk
    const bf16* Ab = nullptr; const float* Af = nullptr;
    float mn = 0.0f, rs = 0.0f;
    if (AMODE == 0) {
        Ab = (const bf16*)Asrc + (size_t)(m0 + sr) * K;
    } else {
        Af = (const float*)Asrc + (size_t)(m0 + sr) * 768;
        float s = inS[m0 + sr], q = inQ[m0 + sr];
        mn = s * (1.0f / 768.0f);
        rs = rsqrtf(q * (1.0f / 768.0f) - mn * mn + 1e-5f);
    }
    const bf16* Brow = &Bt[(size_t)(n0 + sr) * K];
    bool awrite = (AMODE == 1) && (blockIdx.x == 0);
    f32x4 acc[4] = {};
    uint4 a0, a1, a2, a3, b0, b1;
    // prefetch chunk 0
    if (AMODE == 0) {
        a0 = *(const uint4*)&Ab[sk];
        a1 = *(const uint4*)&Ab[32 + sk];
    } else {
        a0 = *(const uint4*)&Af[sk];      a1 = *(const uint4*)&Af[sk + 4];
        a2 = *(const uint4*)&Af[32 + sk]; a3 = *(const uint4*)&Af[32 + sk + 4];
    }
    b0 = *(const uint4*)&Brow[sk];
    b1 = *(const uint4*)&Brow[32 + sk];
    for (int k0 = 0; k0 < K; k0 += 64) {
        __syncthreads();
        if (AMODE == 0) {
            *(uint4*)&As0[sr][sk] = a0;
            *(uint4*)&As1[sr][sk] = a1;
        } else {
#pragma unroll
            for (int half = 0; half < 2; half++) {
                int kabs = k0 + 32 * half;
                float4 v0 = *(float4*)(half ? &a2 : &a0);
                float4 v1 = *(float4*)(half ? &a3 : &a1);
                float4 gg0 = *(const float4*)&ag[kabs + sk];
                float4 gg1 = *(const float4*)&ag[kabs + sk + 4];
                float4 bb0 = *(const float4*)&ab[kabs + sk];
                float4 bb1 = *(const float4*)&ab[kabs + sk + 4];
                float o[8];
                o[0] = (v0.x - mn) * rs * gg0.x + bb0.x;
                o[1] = (v0.y - mn) * rs * gg0.y + bb0.y;
                o[2] = (v0.z - mn) * rs * gg0.z + bb0.z;
                o[3] = (v0.w - mn) * rs * gg0.w + bb0.w;
                o[4] = (v1.x - mn) * rs * gg1.x + bb1.x;
                o[5] = (v1.y - mn) * rs * gg1.y + bb1.y;
                o[6] = (v1.z - mn) * rs * gg1.z + bb1.z;
                o[7] = (v1.w - mn) * rs * gg1.w + bb1.w;
                if (awrite) {
                    *(float4*)&aNormOut[(size_t)(m0 + sr) * 768 + kabs + sk] =
                        make_float4(o[0], o[1], o[2], o[3]);
                    *(float4*)&aNormOut[(size_t)(m0 + sr) * 768 + kabs + sk + 4] =
                        make_float4(o[4], o[5], o[6], o[7]);
                }
                bf16 t8[8];
#pragma unroll
                for (int j = 0; j < 8; j++) t8[j] = (bf16)o[j];
                if (half) *(uint4*)&As1[sr][sk] = *(uint4*)t8;
                else      *(uint4*)&As0[sr][sk] = *(uint4*)t8;
            }
        }
        *(uint4*)&Bs0[sr][sk] = b0;
        *(uint4*)&Bs1[sr][sk] = b1;
        __syncthreads();
        int k2 = k0 + 64; if (k2 >= K) k2 = 0;      // tail: harmless re-read
        if (AMODE == 0) {
            a0 = *(const uint4*)&Ab[k2 + sk];
            a1 = *(const uint4*)&Ab[k2 + 32 + sk];
        } else {
            a0 = *(const uint4*)&Af[k2 + sk];      a1 = *(const uint4*)&Af[k2 + sk + 4];
            a2 = *(const uint4*)&Af[k2 + 32 + sk]; a3 = *(const uint4*)&Af[k2 + 32 + sk + 4];
        }
        b0 = *(const uint4*)&Brow[k2 + sk];
        b1 = *(const uint4*)&Brow[k2 + 32 + sk];
        bf16x8 af0 = *(bf16x8*)&As0[w * 16 + lm][lq * 8];
        bf16x8 af1 = *(bf16x8*)&As1[w * 16 + lm][lq * 8];
#pragma unroll
        for (int nb = 0; nb < 4; nb++) {
            bf16x8 bf0 = *(bf16x8*)&Bs0[nb * 16 + lm][lq * 8];
            acc[nb] = __builtin_amdgcn_mfma_f32_16x16x32_bf16(af0, bf0, acc[nb], 0, 0, 0);
        }
#pragma unroll
        for (int nb = 0; nb < 4; nb++) {
            bf16x8 bf1 = *(bf16x8*)&Bs1[nb * 16 + lm][lq * 8];
            acc[nb] = __builtin_amdgcn_mfma_f32_16x16x32_bf16(af1, bf1, acc[nb], 0, 0, 0);
        }
    }
    // C layout: row = w*16 + lq*4 + r, col = n0 + nb*16 + lm
    if (EPI == 3) {
        float s[4] = {0.f, 0.f, 0.f, 0.f}, q[4] = {0.f, 0.f, 0.f, 0.f};
#pragma unroll
        for (int nb = 0; nb < 4; nb++) {
            int col = n0 + nb * 16 + lm;
            float bia = bias0[col];
#pragma unroll
            for (int r = 0; r < 4; r++) {
                int row = m0 + w * 16 + lq * 4 + r;
                float v = acc[nb][r] + bia + resid[(size_t)row * N + col];
                outF[(size_t)row * N + col] = v;
                s[r] += v; q[r] += v * v;
            }
        }
#pragma unroll
        for (int mk = 1; mk < 16; mk <<= 1)
#pragma unroll
            for (int r = 0; r < 4; r++) {
                s[r] += __shfl_xor(s[r], mk, 64);
                q[r] += __shfl_xor(q[r], mk, 64);
            }
        if (lm == 0) {
#pragma unroll
            for (int r = 0; r < 4; r++) {
                int row = m0 + w * 16 + lq * 4 + r;
                atomicAdd(&outS[row], s[r]);
                atomicAdd(&outQ[row], q[r]);
            }
        }
    } else {
#pragma unroll
        for (int nb = 0; nb < 4; nb++) {
            int col = n0 + nb * 16 + lm;
            float bia;
            bool do_elu = false;
            if (EPI == 0) {
                if (col < 768)       { bia = bias0[col];        do_elu = true; }
                else if (col < 1536) { bia = bias1[col - 768];  do_elu = true; }
                else                 { bia = bias2[col - 1536]; }
            } else {
                bia = bias0[col];
            }
#pragma unroll
            for (int r = 0; r < 4; r++) {
                int row = m0 + w * 16 + lq * 4 + r;
                float v = acc[nb][r] + bia;
                if (EPI == 0) {
                    if (do_elu) v = (v > 0.0f) ? (v + 1.0f) : expf(v);
                } else {
                    v = fmaxf(v, 0.0f);
                }
                outB[(size_t)row * N + col] = (bf16)v;
            }
        }
    }
}

// ---------------- causal linear attention as two MFMA matmuls ----------------
__global__ __launch_bounds__(320) void attn_k(
        const bf16* __restrict__ qkvB, bf16* __restrict__ att) {
    __shared__ __attribute__((aligned(16))) char smem[64000];
    bf16* Qs = (bf16*)smem;            // [80][200]
    bf16* Ks = (bf16*)(smem + 32000);  // [80][200]
    bf16* Aij = (bf16*)smem;           // [80][104]  (overlays Qs after phase 1)
    bf16* VT = (bf16*)(smem + 16640);  // [192][104] (overlays Ks)

    int b = blockIdx.x >> 2, h = blockIdx.x & 3;
    int tid = threadIdx.x;
    int w = tid >> 6, l = tid & 63;
    int lm = l & 15, lq = l >> 4;

    uint4 vreg[6];
#pragma unroll
    for (int u = 0; u < 6; u++) {
        int c = tid + 320 * u;
        int t = c / 24, cc = c % 24;
        int d0 = cc * 8;
        size_t g = (size_t)(t * 8 + b) * NQKV + h * DH + d0;
        uint4 qv = *(const uint4*)&qkvB[g];
        uint4 kv = *(const uint4*)&qkvB[g + 768];
        vreg[u]  = *(const uint4*)&qkvB[g + 1536];
        *(uint4*)&Qs[t * 200 + d0] = qv;
        *(uint4*)&Ks[t * 200 + d0] = kv;
    }
    __syncthreads();

    f32x4 acc[5] = {};
#pragma unroll
    for (int k0 = 0; k0 < 192; k0 += 32) {
        bf16x8 af = *(bf16x8*)&Qs[(w * 16 + lm) * 200 + lq * 8 + k0];
#pragma unroll
        for (int nb = 0; nb < 5; nb++) {
            bf16x8 bfr = *(bf16x8*)&Ks[(nb * 16 + lm) * 200 + lq * 8 + k0];
            acc[nb] = __builtin_amdgcn_mfma_f32_16x16x32_bf16(af, bfr, acc[nb], 0, 0, 0);
        }
    }
    float mval[5][4];
    float rs[4] = {0.f, 0.f, 0.f, 0.f};
#pragma unroll
    for (int nb = 0; nb < 5; nb++)
#pragma unroll
        for (int r = 0; r < 4; r++) {
            int t = w * 16 + lq * 4 + r, tau = nb * 16 + lm;
            float v = (tau <= t) ? acc[nb][r] : 0.0f;
            mval[nb][r] = v;
            rs[r] += v;
        }
#pragma unroll
    for (int mk = 1; mk < 16; mk <<= 1)
#pragma unroll
        for (int r = 0; r < 4; r++) rs[r] += __shfl_xor(rs[r], mk, 64);
    float inv[4];
#pragma unroll
    for (int r = 0; r < 4; r++) inv[r] = 1.0f / (rs[r] + 1e-6f);

    __syncthreads();

#pragma unroll
    for (int nb = 0; nb < 5; nb++)
#pragma unroll
        for (int r = 0; r < 4; r++)
            Aij[(w * 16 + lq * 4 + r) * 104 + nb * 16 + lm] = (bf16)mval[nb][r];
    *(uint2*)&Aij[(tid >> 2) * 104 + 80 + (tid & 3) * 4] = make_uint2(0u, 0u);
#pragma unroll
    for (int u = 0; u < 6; u++) {
        int c = tid + 320 * u;
        int t = c / 24, cc = c % 24;
        int d0 = cc * 8;
        bf16 tmp8[8];
        *(uint4*)tmp8 = vreg[u];
#pragma unroll
        for (int j = 0; j < 8; j++) VT[(d0 + j) * 104 + t] = tmp8[j];
    }
    if (tid < 192) {
        *(uint4*)&VT[tid * 104 + 80] = make_uint4(0u, 0u, 0u, 0u);
        *(uint4*)&VT[tid * 104 + 88] = make_uint4(0u, 0u, 0u, 0u);
    }
    __syncthreads();

#pragma unroll 1
    for (int nc = 0; nc < 12; nc++) {
        f32x4 a2 = {};
#pragma unroll
        for (int k0 = 0; k0 < 96; k0 += 32) {
            bf16x8 af = *(bf16x8*)&Aij[(w * 16 + lm) * 104 + lq * 8 + k0];
            bf16x8 bfr = *(bf16x8*)&VT[(nc * 16 + lm) * 104 + lq * 8 + k0];
            a2 = __builtin_amdgcn_mfma_f32_16x16x32_bf16(af, bfr, a2, 0, 0, 0);
        }
#pragma unroll
        for (int r = 0; r < 4; r++) {
            int t = w * 16 + lq * 4 + r;
            att[(size_t)(t * 8 + b) * DMODEL + h * DH + nc * 16 + lm] =
                (bf16)(a2[r] * inv[r]);
        }
    }
}

// ---------------- final: ln2 (global stats) -> lnf (local stats) + gather ------
__global__ __launch_bounds__(256) void final_k(
        const float* __restrict__ tmp2, const float* __restrict__ sS,
        const float* __restrict__ sQ, const int* __restrict__ act_ts,
        const float* __restrict__ g2, const float* __restrict__ b2,
        const float* __restrict__ gf, const float* __restrict__ bf,
        float* __restrict__ out) {
    __shared__ float sm4[4];
    int ba = blockIdx.x;
    int b = ba / NA;
    int ts = act_ts[ba];
    int t = ts - 1; if (t < 0) t = 0;
    int row = t * 8 + b;
    const float* xr = tmp2 + (size_t)row * DMODEL;
    // ln2 via producer-accumulated stats
    float mn = sS[row] * (1.0f / 768.0f);
    float r2 = rsqrtf(sQ[row] * (1.0f / 768.0f) - mn * mn + 1e-5f);
    int c = threadIdx.x;
    float x0 = (xr[c]       - mn) * r2 * g2[c]       + b2[c];
    float x1 = (xr[c + 256] - mn) * r2 * g2[c + 256] + b2[c + 256];
    float x2 = (xr[c + 512] - mn) * r2 * g2[c + 512] + b2[c + 512];
    // lnf locally
    float m = block_reduce_sum256(x0 + x1 + x2, sm4) * (1.0f / 768.0f);
    float d0 = x0 - m, d1 = x1 - m, d2 = x2 - m;
    float v = block_reduce_sum256(d0 * d0 + d1 * d1 + d2 * d2, sm4) * (1.0f / 768.0f);
    float r = rsqrtf(v + 1e-5f);
    out[ba * 256 + c]            = d0 * r * gf[c] + bf[c];                // mu
    out[48 * 256 + ba * 256 + c] = d1 * r * gf[c + 256] + bf[c + 256];    // logvar
}

extern "C" void kernel_launch(void* const* d_in, const int* in_sizes, int n_in,
                              void* d_out, int out_size, void* d_ws, size_t ws_size,
                              hipStream_t stream) {
    const float* x       = (const float*)d_in[0];
    const int*   y       = (const int*)d_in[1];
    const int*   ind_map = (const int*)d_in[2];
    const int*   act_ts  = (const int*)d_in[3];
    const float* skel_W  = (const float*)d_in[4];
    const float* skel_b  = (const float*)d_in[5];
    const float* muQ     = (const float*)d_in[6];
    const float* sigQ    = (const float*)d_in[7];
    const float* Wq = (const float*)d_in[8];   const float* bq = (const float*)d_in[9];
    const float* Wk = (const float*)d_in[10];  const float* bk = (const float*)d_in[11];
    const float* Wv = (const float*)d_in[12];  const float* bv = (const float*)d_in[13];
    const float* Wo = (const float*)d_in[14];  const float* bo = (const float*)d_in[15];
    const float* W1 = (const float*)d_in[16];  const float* b1 = (const float*)d_in[17];
    const float* W2 = (const float*)d_in[18];  const float* b2 = (const float*)d_in[19];
    const float* ln1_g = (const float*)d_in[20]; const float* ln1_b = (const float*)d_in[21];
    const float* ln2_g = (const float*)d_in[22]; const float* ln2_b = (const float*)d_in[23];
    const float* lnf_g = (const float*)d_in[24]; const float* lnf_b = (const float*)d_in[25];
    float* out = (float*)d_out;

    // ---- workspace layout (all 16B aligned) ----
    char* p = (char*)d_ws;
    const size_t R  = (size_t)NROWS * DMODEL;      // 491520
    float* hF   = (float*)p; p += R * 4;   // residual input to Wo site
    float* h1F  = (float*)p; p += R * 4;   // residual input to W2 site
    float* tmp1 = (float*)p; p += R * 4;   // Wo out (pre-ln1)
    float* tmp2 = (float*)p; p += R * 4;   // W2 out (pre-ln2)
    float* stats = (float*)p; p += 8 * 1280 * 4;  // [site 0..7][sum 640 | sq 640]
    bf16* qkvB  = (bf16*)p;  p += (size_t)NROWS * NQKV * 2;
    bf16* hB    = (bf16*)p;  p += R * 2;   // embed bf16 (layer-0 QKV input)
    bf16* attB  = (bf16*)p;  p += R * 2;
    bf16* ffn1B = (bf16*)p;  p += (size_t)NROWS * FFD * 2;
    bf16* qkvT  = (bf16*)p;  p += (size_t)4 * NQKV * DMODEL * 2;
    bf16* woT   = (bf16*)p;  p += (size_t)4 * DMODEL * DMODEL * 2;
    bf16* w1T   = (bf16*)p;  p += (size_t)4 * FFD * DMODEL * 2;
    bf16* w2T   = (bf16*)p;  p += (size_t)4 * DMODEL * FFD * 2;

    hipMemsetAsync(stats, 0, 8 * 1280 * 4, stream);   // zero LN-stat accumulators
    dim3 gT(32, 72, 16);
    transpose_k<<<gT, 256, 0, stream>>>(Wq, Wk, Wv, Wo, W1, W2, qkvT, woT, w1T, w2T);
    embed_k<<<NROWS, 256, 0, stream>>>(x, y, ind_map, skel_W, skel_b, muQ, sigQ, hF, hB);

    dim3 gQKV(NQKV / 64, 10);
    dim3 g768(12, 10);
    dim3 g1024(16, 10);
    for (int l = 0; l < 4; l++) {
        const bf16* qkvTl = qkvT + (size_t)l * NQKV * DMODEL;
        const bf16* woTl  = woT  + (size_t)l * DMODEL * DMODEL;
        const bf16* w1Tl  = w1T  + (size_t)l * FFD * DMODEL;
        const bf16* w2Tl  = w2T  + (size_t)l * DMODEL * FFD;
        float* sS1 = stats + (size_t)(l * 2 + 0) * 1280; float* sQ1 = sS1 + 640;
        float* sS2 = stats + (size_t)(l * 2 + 1) * 1280; float* sQ2 = sS2 + 640;
        // QKV: layer0 reads embed bf16; layers 1-3 fuse ln2 of previous layer
        if (l == 0) {
            gemm_mfma<0, 0><<<gQKV, 256, 0, stream>>>(hB, qkvTl,
                    bq, bk, bv, nullptr,
                    nullptr, nullptr, nullptr, nullptr, nullptr,
                    nullptr, qkvB, nullptr, nullptr, NROWS, NQKV, DMODEL);
        } else {
            float* pS2 = stats + (size_t)((l - 1) * 2 + 1) * 1280; float* pQ2 = pS2 + 640;
            gemm_mfma<1, 0><<<gQKV, 256, 0, stream>>>(tmp2, qkvTl,
                    bq + l * DMODEL, bk + l * DMODEL, bv + l * DMODEL, nullptr,
                    pS2, pQ2, ln2_g + (l - 1) * DMODEL, ln2_b + (l - 1) * DMODEL, hF,
                    nullptr, qkvB, nullptr, nullptr, NROWS, NQKV, DMODEL);
        }
        attn_k<<<32, 320, 0, stream>>>(qkvB, attB);
        // Wo: att @ Wo + bo + hF -> tmp1 (f32) + ln1 stats
        gemm_mfma<0, 3><<<g768, 256, 0, stream>>>(attB, woTl,
                bo + l * DMODEL, nullptr, nullptr, hF,
                nullptr, nullptr, nullptr, nullptr, nullptr,
                tmp1, nullptr, sS1, sQ1, NROWS, DMODEL, DMODEL);
        // W1: relu(ln1(tmp1) @ W1 + b1) -> ffn1B; block x==0 writes h1F
        gemm_mfma<1, 2><<<g1024, 256, 0, stream>>>(tmp1, w1Tl,
                b1 + l * FFD, nullptr, nullptr, nullptr,
                sS1, sQ1, ln1_g + l * DMODEL, ln1_b + l * DMODEL, h1F,
                nullptr, ffn1B, nullptr, nullptr, NROWS, FFD, DMODEL);
        // W2: ffn1 @ W2 + b2 + h1F -> tmp2 (f32) + ln2 stats
        gemm_mfma<0, 3><<<g768, 256, 0, stream>>>(ffn1B, w2Tl,
                b2 + l * DMODEL, nullptr, nullptr, h1F,
                nullptr, nullptr, nullptr, nullptr, nullptr,
                tmp2, nullptr, sS2, sQ2, NROWS, DMODEL, FFD);
    }

    float* sS2_3 = stats + (size_t)(3 * 2 + 1) * 1280; float* sQ2_3 = sS2_3 + 640;
    final_k<<<48, 256, 0, stream>>>(tmp2, sS2_3, sQ2_3, act_ts,
            ln2_g + 3 * DMODEL, ln2_b + 3 * DMODEL, lnf_g, lnf_b, out);
}